// Round 6
// baseline (395.780 us; speedup 1.0000x reference)
//
#include <hip/hip_runtime.h>
#include <hip/hip_bf16.h>

// GCN R6: R5 with the GEMM LDS alignment bug fixed.
// Weight slab in LDS uses 16B-chunk XOR swizzle (ch ^ (c&31)) instead of a
// misaligned 250-elem pad (R5's bug: 500B rows broke ds_*_b128 alignment).
// Barrier-free GEMM K-loop (A streamed global->MFMA frags), cast+hist+
// transpose fused prep, REP=16 CSR counters, SpMM with 8 gathers in flight.

#define N_NODES 50000
#define N_EDGES 800000
#define KDIM 256
#define REP 16
#define NC (N_NODES * REP)            // 800000 replicated counters
#define NB2 ((NC + 1023) / 1024)      // 782 scan blocks
#define NC_PAD (NB2 * 1024)           // 800768

// prep kernel block ranges
#define PB_CAST 6250                  // 50000*256/8/256
#define PB_HIST 782                   // ceil(800000/1024)
#define PB_TR   640                   // 163840/256

typedef __attribute__((ext_vector_type(8))) short short8;
typedef __attribute__((ext_vector_type(4))) float f32x4;

__device__ __forceinline__ ushort f2bf(float f) {
    union { float f; unsigned u; } x; x.f = f;
    unsigned r = x.u + 0x7fffu + ((x.u >> 16) & 1u);  // RTN-even
    return (ushort)(r >> 16);
}
__device__ __forceinline__ float bf2f(ushort u) {
    union { unsigned u; float f; } x; x.u = ((unsigned)u) << 16;
    return x.f;
}

// ---------------- prep: cast x->bf16 | hist | weight transposes ----------
__global__ __launch_bounds__(256) void prep_kernel(
        const float* __restrict__ x, ushort* __restrict__ xb,
        const int* __restrict__ rows, int* __restrict__ counts,
        const float* __restrict__ W1, const float* __restrict__ W2,
        const float* __restrict__ W3, ushort* __restrict__ Wt1,
        ushort* __restrict__ Wt2, ushort* __restrict__ Wt3) {
    int b = blockIdx.x, t = threadIdx.x;
    if (b < PB_CAST) {
        int i = (b * 256 + t) * 8;
        float4 f0 = *(const float4*)&x[i];
        float4 f1 = *(const float4*)&x[i + 4];
        short8 o;
        o[0] = (short)f2bf(f0.x); o[1] = (short)f2bf(f0.y);
        o[2] = (short)f2bf(f0.z); o[3] = (short)f2bf(f0.w);
        o[4] = (short)f2bf(f1.x); o[5] = (short)f2bf(f1.y);
        o[6] = (short)f2bf(f1.z); o[7] = (short)f2bf(f1.w);
        *(short8*)&xb[i] = o;
    } else if (b < PB_CAST + PB_HIST) {
        int e0 = (b - PB_CAST) * 1024 + t * 4;
        if (e0 + 3 < N_EDGES) {
            int4 r4 = *(const int4*)&rows[e0];
            atomicAdd(&counts[(r4.x << 4) | ((e0    ) & 15)], 1);
            atomicAdd(&counts[(r4.y << 4) | ((e0 + 1) & 15)], 1);
            atomicAdd(&counts[(r4.z << 4) | ((e0 + 2) & 15)], 1);
            atomicAdd(&counts[(r4.w << 4) | ((e0 + 3) & 15)], 1);
        } else {
            for (int j = 0; j < 4; j++) {
                int e = e0 + j;
                if (e < N_EDGES) atomicAdd(&counts[(rows[e] << 4) | (e & 15)], 1);
            }
        }
    } else {
        int id = (b - PB_CAST - PB_HIST) * 256 + t;   // 0..163839
        if (id < 65536) {
            int n = id >> 8, k = id & 255;
            Wt1[n * 256 + k] = f2bf(W1[k * 256 + n]);
        } else if (id < 131072) {
            int i = id - 65536, n = i >> 8, k = i & 255;
            Wt2[n * 256 + k] = f2bf(W2[k * 256 + n]);
        } else {
            int i = id - 131072, n = i >> 8, k = i & 255;
            Wt3[n * 256 + k] = f2bf(W3[k * 128 + n]);
        }
    }
}

// ---------------- hierarchical scan over NC replicated counters ------------

__global__ __launch_bounds__(256) void scan_sums(const int* __restrict__ counts,
                                                 int* __restrict__ bsum) {
    __shared__ int ws[4];
    int b = blockIdx.x, t = threadIdx.x, lane = t & 63, wv = t >> 6;
    int4 v = *(const int4*)&counts[b * 1024 + t * 4];
    int s = v.x + v.y + v.z + v.w;
    #pragma unroll
    for (int off = 32; off >= 1; off >>= 1) s += __shfl_down(s, off, 64);
    if (lane == 0) ws[wv] = s;
    __syncthreads();
    if (t == 0) bsum[b] = ws[0] + ws[1] + ws[2] + ws[3];
}

// single block, 1024 threads: exclusive scan of NB2(=782) block sums + total.
__global__ __launch_bounds__(1024) void scan_block(const int* __restrict__ bsum,
                                                   int* __restrict__ boff,
                                                   int* __restrict__ rp16, int nb) {
    __shared__ int ws[16];
    int t = threadIdx.x, lane = t & 63, wv = t >> 6;
    int v = (t < nb) ? bsum[t] : 0;
    int incl = v;
    #pragma unroll
    for (int off = 1; off < 64; off <<= 1) {
        int u = __shfl_up(incl, off, 64);
        if (lane >= off) incl += u;
    }
    if (lane == 63) ws[wv] = incl;
    __syncthreads();
    int wo = 0;
    #pragma unroll
    for (int j = 0; j < 15; j++) wo += (j < wv) ? ws[j] : 0;
    if (t < nb) boff[t] = wo + incl - v;
    if (t == 1023) rp16[NC] = wo + incl;   // == N_EDGES
}

__global__ __launch_bounds__(256) void scan_apply(int* __restrict__ counts,
                                                  const int* __restrict__ boff,
                                                  int* __restrict__ rp16) {
    __shared__ int ws[4];
    int b = blockIdx.x, t = threadIdx.x, lane = t & 63, wv = t >> 6;
    int i = b * 1024 + t * 4;
    int4 v = *(const int4*)&counts[i];
    int s0 = v.x, s01 = s0 + v.y, s012 = s01 + v.z, tsum = s012 + v.w;
    int incl = tsum;
    #pragma unroll
    for (int off = 1; off < 64; off <<= 1) {
        int u = __shfl_up(incl, off, 64);
        if (lane >= off) incl += u;
    }
    if (lane == 63) ws[wv] = incl;
    __syncthreads();
    int woff = 0;
    #pragma unroll
    for (int j = 0; j < 3; j++) woff += (j < wv) ? ws[j] : 0;
    int base = boff[b] + woff + incl - tsum;
    if (i < NC)     rp16[i]     = base;
    if (i + 1 < NC) rp16[i + 1] = base + s0;
    if (i + 2 < NC) rp16[i + 2] = base + s01;
    if (i + 3 < NC) rp16[i + 3] = base + s012;
    *(int4*)&counts[i] = make_int4(0, 0, 0, 0);
}

__global__ void scatter_kernel(const int* __restrict__ rows, const int* __restrict__ cols,
                               const float* __restrict__ vals, const int* __restrict__ rp16,
                               int* __restrict__ counts, int2* __restrict__ cv) {
    int e = blockIdx.x * blockDim.x + threadIdx.x;
    if (e < N_EDGES) {
        int idx = (rows[e] << 4) | (e & 15);
        int pos = rp16[idx] + atomicAdd(&counts[idx], 1);
        cv[pos] = make_int2(cols[e], __float_as_int(vals[e]));
    }
}

// ---------------- GEMM: C[M,N] = A[M,256] @ Wt[N,256]^T, bf16 ----------
// Block = 256 threads = 4 waves; block tile 256 rows x 128 cols.
// Full 128-col weight slab staged in LDS once (64 KB exactly), 16B chunks
// XOR-swizzled: chunk ch of column c lives at (ch ^ (c&31)). All addresses
// 16B-aligned; read phase is bank-uniform (8 accesses/bank per wave b128).
// A fragments loaded DIRECTLY from global (contiguous short8 per lane);
// K-loop fully unrolled, no barriers -> loads pipeline under MFMAs.

__global__ __launch_bounds__(256) void gemm_kernel(
        const ushort* __restrict__ A, const ushort* __restrict__ Wt,
        ushort* __restrict__ C, int M, int N) {
    __shared__ ushort Ws[128 * 256];   // 65536 B

    int t = threadIdx.x, lane = t & 63, w = t >> 6;
    int row0 = blockIdx.x * 256 + w * 64;
    int col0 = blockIdx.y * 128;
    int q = lane >> 4, mi = lane & 15;

    // stage weight slab: 128 cols x 32 chunks of 8 bf16 (16 B), xor-swizzled
    #pragma unroll
    for (int i = 0; i < 16; i++) {
        int u = i * 256 + t;          // 0..4095
        int c = u >> 5, ch = u & 31;
        *(short8*)&Ws[c * 256 + (ch ^ (c & 31)) * 8] =
            *(const short8*)&Wt[(col0 + c) * KDIM + ch * 8];
    }
    __syncthreads();

    f32x4 acc[4][8];
    #pragma unroll
    for (int i = 0; i < 4; i++)
        #pragma unroll
        for (int j = 0; j < 8; j++) acc[i][j] = (f32x4)0.f;

    #pragma unroll
    for (int ks = 0; ks < 8; ks++) {
        int kc = ks * 4 + q;          // 16B-chunk index of this lane's k-slice
        short8 af[4], bf[8];
        #pragma unroll
        for (int mt = 0; mt < 4; mt++) {
            int gr = row0 + mt * 16 + mi;
            if (gr >= M) gr = M - 1;
            af[mt] = *(const short8*)&A[gr * KDIM + kc * 8];
        }
        #pragma unroll
        for (int nt = 0; nt < 8; nt++) {
            int cc = nt * 16 + mi;
            bf[nt] = *(const short8*)&Ws[cc * 256 + (kc ^ (cc & 31)) * 8];
        }
        #pragma unroll
        for (int mt = 0; mt < 4; mt++)
            #pragma unroll
            for (int nt = 0; nt < 8; nt++)
                acc[mt][nt] = __builtin_amdgcn_mfma_f32_16x16x32_bf16(
                    af[mt], bf[nt], acc[mt][nt], 0, 0, 0);
    }

    // C/D layout: col = lane&15, row = q*4 + reg
    #pragma unroll
    for (int mt = 0; mt < 4; mt++) {
        #pragma unroll
        for (int r = 0; r < 4; r++) {
            int grow = row0 + mt * 16 + q * 4 + r;
            if (grow < M) {
                #pragma unroll
                for (int nt = 0; nt < 8; nt++)
                    C[grow * N + col0 + nt * 16 + mi] = f2bf(acc[mt][nt][r]);
            }
        }
    }
}

// ---------------- SpMM (CSR): wave per row, 8 gathers in flight ----------
// Lane = ep*FL + fl; each ep group owns 8 contiguous edges per iteration.

template <int F, bool RELU, bool OUT_BF16>
__global__ __launch_bounds__(256) void spmm_kernel(
        const ushort* __restrict__ H, const int* __restrict__ rp16,
        const int2* __restrict__ cv, const float* __restrict__ bias,
        void* __restrict__ out, int nrows) {
    constexpr int FL = F / 8;       // 32 (F=256) / 16 (F=128)
    constexpr int EP = 64 / FL;     // 2 / 4
    constexpr int STEP = EP * 8;    // 16 / 32 edges per iteration
    int wave = threadIdx.x >> 6, lane = threadIdx.x & 63;
    int r = blockIdx.x * 4 + wave;
    if (r >= nrows) return;
    int fl = lane % FL, ep = lane / FL;
    const ushort* Hl = H + fl * 8;

    float acc[8];
    #pragma unroll
    for (int j = 0; j < 8; j++) acc[j] = 0.f;

    int start = rp16[r * REP], end = rp16[r * REP + REP];
    for (int base = start; base < end; base += STEP) {
        int e0 = base + ep * 8;
        int2 m[8];
        #pragma unroll
        for (int i = 0; i < 8; i++) m[i] = cv[e0 + i];   // may overread pad
        int c[8]; float v[8];
        #pragma unroll
        for (int i = 0; i < 8; i++) {
            bool p = (e0 + i) < end;
            c[i] = p ? m[i].x : 0;
            v[i] = p ? __int_as_float(m[i].y) : 0.f;
        }
        short8 h[8];
        #pragma unroll
        for (int i = 0; i < 8; i++) h[i] = *(const short8*)&Hl[(size_t)c[i] * F];
        #pragma unroll
        for (int i = 0; i < 8; i++)
            #pragma unroll
            for (int j = 0; j < 8; j++)
                acc[j] += v[i] * bf2f((ushort)h[i][j]);
    }

    #pragma unroll
    for (int off = FL; off < 64; off <<= 1)
        #pragma unroll
        for (int j = 0; j < 8; j++) acc[j] += __shfl_down(acc[j], off, 64);

    if (ep == 0) {
        #pragma unroll
        for (int j = 0; j < 8; j++) {
            float o = acc[j] + bias[fl * 8 + j];
            if (RELU) o = fmaxf(o, 0.f);
            acc[j] = o;
        }
        if (OUT_BF16) {
            short8 ob;
            #pragma unroll
            for (int j = 0; j < 8; j++) ob[j] = (short)f2bf(acc[j]);
            *(short8*)((ushort*)out + (size_t)r * F + fl * 8) = ob;
        } else {
            float* of = (float*)out + (size_t)r * F + fl * 8;
            *(float4*)&of[0] = make_float4(acc[0], acc[1], acc[2], acc[3]);
            *(float4*)&of[4] = make_float4(acc[4], acc[5], acc[6], acc[7]);
        }
    }
}

// ---------------- launch ----------------

extern "C" void kernel_launch(void* const* d_in, const int* in_sizes, int n_in,
                              void* d_out, int out_size, void* d_ws, size_t ws_size,
                              hipStream_t stream) {
    const float* x    = (const float*)d_in[0];
    const float* av   = (const float*)d_in[1];
    const int*   rows = (const int*)d_in[2];
    const int*   cols = (const int*)d_in[3];
    const float* W1   = (const float*)d_in[4];
    const float* b1   = (const float*)d_in[5];
    const float* W2   = (const float*)d_in[6];
    const float* b2   = (const float*)d_in[7];
    const float* W3   = (const float*)d_in[8];
    const float* b3   = (const float*)d_in[9];
    float* out = (float*)d_out;

    const int N = N_NODES, E = N_EDGES;

    char* p = (char*)d_ws;
    auto carve = [&](size_t bytes) {
        void* q = (void*)p;
        p += (bytes + 255) & ~(size_t)255;
        return q;
    };
    ushort* xb   = (ushort*)carve((size_t)N * 256 * 2);
    ushort* bufG = (ushort*)carve((size_t)N * 256 * 2);
    ushort* bufH = (ushort*)carve((size_t)N * 256 * 2);
    ushort* Wt1  = (ushort*)carve((size_t)256 * 256 * 2);
    ushort* Wt2  = (ushort*)carve((size_t)256 * 256 * 2);
    ushort* Wt3  = (ushort*)carve((size_t)128 * 256 * 2);
    int*    rp16   = (int*)carve((size_t)(NC + 1) * 4);
    int*    counts = (int*)carve((size_t)NC_PAD * 4);
    int*    bsum   = (int*)carve((size_t)NB2 * 4);
    int*    boff   = (int*)carve((size_t)NB2 * 4);
    int2*   cv     = (int2*)carve((size_t)(E + 64) * 8);

    hipMemsetAsync(counts, 0, (size_t)NC_PAD * 4, stream);
    prep_kernel<<<PB_CAST + PB_HIST + PB_TR, 256, 0, stream>>>(
        x, xb, rows, counts, W1, W2, W3, Wt1, Wt2, Wt3);

    scan_sums<<<NB2, 256, 0, stream>>>(counts, bsum);
    scan_block<<<1, 1024, 0, stream>>>(bsum, boff, rp16, NB2);
    scan_apply<<<NB2, 256, 0, stream>>>(counts, boff, rp16);
    scatter_kernel<<<(E + 255) / 256, 256, 0, stream>>>(rows, cols, av, rp16, counts, cv);

    dim3 g2((N + 255) / 256, 2);   // 196 x 2
    dim3 g1((N + 255) / 256, 1);
    int spmm_blocks = (N + 3) / 4;

    gemm_kernel<<<g2, 256, 0, stream>>>(xb, Wt1, bufG, N, 256);
    spmm_kernel<256, true, true><<<spmm_blocks, 256, 0, stream>>>(bufG, rp16, cv, b1, bufH, N);
    gemm_kernel<<<g2, 256, 0, stream>>>(bufH, Wt2, bufG, N, 256);
    spmm_kernel<256, true, true><<<spmm_blocks, 256, 0, stream>>>(bufG, rp16, cv, b2, bufH, N);
    gemm_kernel<<<g1, 256, 0, stream>>>(bufH, Wt3, bufG, N, 128);
    spmm_kernel<128, false, false><<<spmm_blocks, 256, 0, stream>>>(bufG, rp16, cv, b3, out, N);
}